// Round 7
// baseline (377.611 us; speedup 1.0000x reference)
//
#include <hip/hip_runtime.h>

#define Bn 2
#define Hn 16
#define Tn 2048
#define Sn 2048
#define Wd 1024
#define Dh 64

typedef __attribute__((ext_vector_type(8))) short s16x8;
typedef __attribute__((ext_vector_type(4))) short s16x4;
typedef __attribute__((ext_vector_type(4))) float f32x4;

#define MFMA(a, b, c) __builtin_amdgcn_mfma_f32_16x16x32_bf16((a), (b), (c), 0, 0, 0)

__device__ __forceinline__ s16x8 ld8(const short* p) { return *(const s16x8*)p; }

// fp32 -> bf16, round-to-nearest-even (for V staging and final outputs)
__device__ __forceinline__ short f2bf(float f) {
    unsigned u = __builtin_bit_cast(unsigned, f);
    u += 0x7FFFu + ((u >> 16) & 1u);
    return (short)(u >> 16);
}
// fp32 -> bf16, truncation (cheap; used for P with den computed from the SAME
// truncated values, so the softmax ratio stays self-consistent)
__device__ __forceinline__ short f2bf_tr(float f) {
    return (short)(__builtin_bit_cast(unsigned, f) >> 16);
}
__device__ __forceinline__ float bf2f(short s) {
    unsigned u = ((unsigned)(unsigned short)s) << 16;
    return __builtin_bit_cast(float, u);
}

// 8 fp32 -> bf16x8 fragment load (32B, two float4)
__device__ __forceinline__ s16x8 ld8f(const float* p) {
    const float4* q = (const float4*)p;
    float4 a = q[0], b = q[1];
    s16x8 o;
    o[0] = f2bf(a.x); o[1] = f2bf(a.y); o[2] = f2bf(a.z); o[3] = f2bf(a.w);
    o[4] = f2bf(b.x); o[5] = f2bf(b.y); o[6] = f2bf(b.z); o[7] = f2bf(b.w);
    return o;
}

// LDS row stride in bf16 elems: 80B rows; 16B-aligned (b128 ok), 8B-aligned for b64
#define LSTR 40

// ---------------------------------------------------------------------------
// Attention: out[b,t,h*64+d] = softmax_s((q.k)/8) @ V, no max-subtraction
// (scores ~ N(0,1), exp cannot overflow fp32).
// Block: 512 thr = 8 waves, 128 q-rows/block (16 per wave). Grid 512 blocks
// (XCD-swizzled so all 16 q-tiles of one head share an XCD L2).
// Pipelined: double-buffered Vt, ONE barrier/iter, next chunk's K-frags and
// V values prefetched into registers during current chunk's compute.
// ---------------------------------------------------------------------------
__global__ __launch_bounds__(512, 4) void attn_fused(
    const float* __restrict__ x, const float* __restrict__ ck,
    const float* __restrict__ cv, short* __restrict__ ao)
{
    __shared__ short Vt[2][Dh * LSTR];    // V transposed [d][s(32)], dbl-buffered
    __shared__ short Pl[8 * 16 * LSTR];   // per-wave P tile [16 q][32 s]

    const int tid  = threadIdx.x;
    const int w    = tid >> 6;           // wave 0..7
    const int l    = tid & 63;
    const int quad = l >> 4;
    const int l16  = l & 15;

    // XCD swizzle: blk%8 selects XCD (heuristic); all qt of one (b,h) share it
    const int i0  = blockIdx.x;
    const int bhl = i0 & 7, rest = i0 >> 3;
    const int qt  = rest & 15, bhh = rest >> 4;
    const int bh  = bhh * 8 + bhl;
    const int b   = bh >> 4, h = bh & 15;

    const int qrow0 = qt * 128 + w * 16;

    // Q A-fragments for this wave's 16 rows (held all loop)
    s16x8 aq[2];
#pragma unroll
    for (int c = 0; c < 2; ++c)
        aq[c] = ld8f(x + (size_t)(b * Tn + qrow0 + l16) * Wd + h * Dh + c * 32 + quad * 8);

    f32x4 oacc[4];
    float dn[4];
#pragma unroll
    for (int nt = 0; nt < 4; ++nt) {
        oacc[nt][0] = 0.f; oacc[nt][1] = 0.f; oacc[nt][2] = 0.f; oacc[nt][3] = 0.f;
    }
#pragma unroll
    for (int r = 0; r < 4; ++r) dn[r] = 0.f;

    // V staging task: this thread owns (d = vd, 4 s-rows starting at vs*4)
    const int vd = tid & 63, vs = tid >> 6;
    const float* vbase = cv + (size_t)(b * Sn) * Wd + h * Dh + vd;
    const float* kbase = ck + (size_t)(b * Sn) * Wd + h * Dh;

    short* Pw = Pl + w * (16 * LSTR);

    // ---- prologue: chunk 0 ----
    float4 vv;
    vv.x = vbase[(size_t)(vs * 4 + 0) * Wd];
    vv.y = vbase[(size_t)(vs * 4 + 1) * Wd];
    vv.z = vbase[(size_t)(vs * 4 + 2) * Wd];
    vv.w = vbase[(size_t)(vs * 4 + 3) * Wd];
    s16x8 bk[2][2];
#pragma unroll
    for (int n = 0; n < 2; ++n)
#pragma unroll
        for (int c = 0; c < 2; ++c)
            bk[n][c] = ld8f(kbase + (size_t)(n * 16 + l16) * Wd + c * 32 + quad * 8);
    {
        s16x4 pv;
        pv[0] = f2bf(vv.x); pv[1] = f2bf(vv.y); pv[2] = f2bf(vv.z); pv[3] = f2bf(vv.w);
        *(s16x4*)&Vt[0][vd * LSTR + vs * 4] = pv;
    }
    __syncthreads();

    for (int it = 0; it < Sn / 32; ++it) {
        const bool more = (it < Sn / 32 - 1);
        const int s1 = (it + 1) * 32;
        // ---- prefetch chunk it+1 (loads in flight during compute below) ----
        float4 vn;
        s16x8 bkn[2][2];
        if (more) {
            vn.x = vbase[(size_t)(s1 + vs * 4 + 0) * Wd];
            vn.y = vbase[(size_t)(s1 + vs * 4 + 1) * Wd];
            vn.z = vbase[(size_t)(s1 + vs * 4 + 2) * Wd];
            vn.w = vbase[(size_t)(s1 + vs * 4 + 3) * Wd];
#pragma unroll
            for (int n = 0; n < 2; ++n)
#pragma unroll
                for (int c = 0; c < 2; ++c)
                    bkn[n][c] = ld8f(kbase + (size_t)(s1 + n * 16 + l16) * Wd + c * 32 + quad * 8);
        }

        // ---- compute chunk it ----
        const short* Vc = Vt[it & 1];
        const f32x4 z = {0.f, 0.f, 0.f, 0.f};
        f32x4 sc0 = MFMA(aq[0], bk[0][0], z);
        sc0 = MFMA(aq[1], bk[0][1], sc0);
        f32x4 sc1 = MFMA(aq[0], bk[1][0], z);
        sc1 = MFMA(aq[1], bk[1][1], sc1);
#pragma unroll
        for (int r = 0; r < 4; ++r) {
            short t0 = f2bf_tr(__expf(sc0[r] * 0.125f));
            short t1 = f2bf_tr(__expf(sc1[r] * 0.125f));
            dn[r] += bf2f(t0) + bf2f(t1);          // den from truncated values
            Pw[(quad * 4 + r) * LSTR + l16]      = t0;
            Pw[(quad * 4 + r) * LSTR + 16 + l16] = t1;
        }
        __asm__ __volatile__("" ::: "memory");     // no hoist of aliased read
        s16x8 ap = *(const s16x8*)&Pw[l16 * LSTR + quad * 8];
#pragma unroll
        for (int nt = 0; nt < 4; ++nt) {
            s16x8 bv = *(const s16x8*)&Vc[(nt * 16 + l16) * LSTR + quad * 8];
            oacc[nt] = MFMA(ap, bv, oacc[nt]);
        }

        // ---- stage chunk it+1 into the other Vt buffer, single barrier ----
        if (more) {
            s16x4 pv;
            pv[0] = f2bf(vn.x); pv[1] = f2bf(vn.y); pv[2] = f2bf(vn.z); pv[3] = f2bf(vn.w);
            *(s16x4*)&Vt[(it + 1) & 1][vd * LSTR + vs * 4] = pv;
#pragma unroll
            for (int n = 0; n < 2; ++n)
#pragma unroll
                for (int c = 0; c < 2; ++c)
                    bk[n][c] = bkn[n][c];
            __syncthreads();
        }
    }

    // epilogue: reduce den across the 16 column-lanes, scale, store bf16 ws
#pragma unroll
    for (int r = 0; r < 4; ++r) {
        float d = dn[r];
        d += __shfl_xor(d, 1);
        d += __shfl_xor(d, 2);
        d += __shfl_xor(d, 4);
        d += __shfl_xor(d, 8);
        float inv = 1.0f / d;
        int t = qrow0 + quad * 4 + r;
#pragma unroll
        for (int nt = 0; nt < 4; ++nt)
            ao[(size_t)(b * Tn + t) * Wd + h * Dh + nt * 16 + l16] =
                f2bf(oacc[nt][r] * inv);
    }
}

// ---------------------------------------------------------------------------
// Projection: out[M=4096][N=1024] = A[M][K=1024] @ Wp[N][K]^T + bias (fp32 out)
// A = bf16 ws; Wp fp32 (converted on stage). Block 256 thr = 4 waves;
// tile 128(M) x 64(N), each wave 32 rows (8 MFMA per 32-k stage round).
// ---------------------------------------------------------------------------
__global__ __launch_bounds__(256, 2) void proj_gemm(
    const short* __restrict__ A, const float* __restrict__ Wp,
    const float* __restrict__ bias, float* __restrict__ out)
{
    __shared__ short Wb[64 * LSTR];

    const int tid  = threadIdx.x;
    const int w    = tid >> 6;
    const int l    = tid & 63;
    const int quad = l >> 4;
    const int l16  = l & 15;

    const int bn = blockIdx.x & 15;    // Wd/64 = 16
    const int bm = blockIdx.x >> 4;    // 4096/128 = 32
    const int m0 = bm * 128 + w * 32;
    const int n0 = bn * 64;

    const int rr = tid >> 2;   // staging row 0..63
    const int sg = tid & 3;    // staging 16B segment 0..3

    f32x4 acc[2][4];
#pragma unroll
    for (int mi = 0; mi < 2; ++mi)
#pragma unroll
        for (int nt = 0; nt < 4; ++nt) {
            acc[mi][nt][0] = 0.f; acc[mi][nt][1] = 0.f;
            acc[mi][nt][2] = 0.f; acc[mi][nt][3] = 0.f;
        }

    for (int k0 = 0; k0 < Wd; k0 += 32) {
        s16x8 wv = ld8f(Wp + (size_t)(n0 + rr) * Wd + k0 + sg * 8);
        __syncthreads();
        *(s16x8*)&Wb[rr * LSTR + sg * 8] = wv;
        __syncthreads();
#pragma unroll
        for (int mi = 0; mi < 2; ++mi) {
            s16x8 a = ld8(A + (size_t)(m0 + mi * 16 + l16) * Wd + k0 + quad * 8);
#pragma unroll
            for (int nt = 0; nt < 4; ++nt) {
                s16x8 bfr = *(const s16x8*)&Wb[(nt * 16 + l16) * LSTR + quad * 8];
                acc[mi][nt] = MFMA(a, bfr, acc[mi][nt]);
            }
        }
    }

#pragma unroll
    for (int nt = 0; nt < 4; ++nt) {
        float bv = bias[n0 + nt * 16 + l16];
#pragma unroll
        for (int mi = 0; mi < 2; ++mi)
#pragma unroll
            for (int r = 0; r < 4; ++r)
                out[(size_t)(m0 + mi * 16 + quad * 4 + r) * Wd + n0 + nt * 16 + l16] =
                    acc[mi][nt][r] + bv;
    }
}

extern "C" void kernel_launch(void* const* d_in, const int* in_sizes, int n_in,
                              void* d_out, int out_size, void* d_ws, size_t ws_size,
                              hipStream_t stream) {
    const float* x  = (const float*)d_in[0];   // [2,2048,1024] fp32
    const float* ck = (const float*)d_in[1];   // [2,2048,1024] fp32
    const float* cv = (const float*)d_in[2];   // [2,2048,1024] fp32
    const float* wp = (const float*)d_in[3];   // [1024,1024]   fp32
    const float* bp = (const float*)d_in[4];   // [1024]        fp32

    short* attn_ws = (short*)d_ws;             // [4096][1024] bf16, 8.4 MB

    attn_fused<<<dim3(Bn * Hn * (Tn / 128)), dim3(512), 0, stream>>>(x, ck, cv, attn_ws);
    proj_gemm<<<dim3((Bn * Tn / 128) * (Wd / 64)), dim3(256), 0, stream>>>(
        attn_ws, wp, bp, (float*)d_out);
}

// Round 8
// 293.390 us; speedup vs baseline: 1.2871x; 1.2871x over previous
//
#include <hip/hip_runtime.h>

#define Bn 2
#define Hn 16
#define Tn 2048
#define Sn 2048
#define Wd 1024
#define Dh 64

typedef __attribute__((ext_vector_type(8))) short s16x8;
typedef __attribute__((ext_vector_type(4))) short s16x4;
typedef __attribute__((ext_vector_type(4))) float f32x4;

#define MFMA(a, b, c) __builtin_amdgcn_mfma_f32_16x16x32_bf16((a), (b), (c), 0, 0, 0)

__device__ __forceinline__ s16x8 ld8(const short* p) { return *(const s16x8*)p; }

// fp32 -> bf16 round-to-nearest-even
__device__ __forceinline__ short f2bf(float f) {
    unsigned u = __builtin_bit_cast(unsigned, f);
    u += 0x7FFFu + ((u >> 16) & 1u);
    return (short)(u >> 16);
}
// truncation variant (P weights; denominator uses the same truncated values)
__device__ __forceinline__ short f2bf_tr(float f) {
    return (short)(__builtin_bit_cast(unsigned, f) >> 16);
}
__device__ __forceinline__ float bf2f(short s) {
    unsigned u = ((unsigned)(unsigned short)s) << 16;
    return __builtin_bit_cast(float, u);
}

// ---------------------------------------------------------------------------
// fp32 -> bf16 bulk convert with scale (8 elems/thread, coalesced)
// ---------------------------------------------------------------------------
__global__ void cvt_scale(const float* __restrict__ in, short* __restrict__ out,
                          int n, float s) {
    int i = (blockIdx.x * 256 + threadIdx.x) * 8;
    if (i < n) {
        float4 a = *(const float4*)(in + i);
        float4 b = *(const float4*)(in + i + 4);
        s16x8 o;
        o[0] = f2bf(a.x * s); o[1] = f2bf(a.y * s); o[2] = f2bf(a.z * s); o[3] = f2bf(a.w * s);
        o[4] = f2bf(b.x * s); o[5] = f2bf(b.y * s); o[6] = f2bf(b.z * s); o[7] = f2bf(b.w * s);
        *(s16x8*)(out + i) = o;
    }
}

// ---------------------------------------------------------------------------
// V -> V^T bf16: cv[b,s,h*64+d] -> vt[(b*16+h)*64+d][s].  64x64 tiles via LDS.
// ---------------------------------------------------------------------------
__global__ __launch_bounds__(256) void vtrans(const float* __restrict__ cv,
                                              short* __restrict__ vt) {
    __shared__ short T[64][68];
    const int st = blockIdx.x & 31;          // s tile
    const int bh = blockIdx.x >> 5;          // 0..31
    const int b = bh >> 4, h = bh & 15;
    const int tid = threadIdx.x;
#pragma unroll
    for (int i = 0; i < 4; ++i) {
        int f = i * 256 + tid, sr = f >> 4, c4 = f & 15;
        float4 v = *(const float4*)(cv + (size_t)(b * Sn + st * 64 + sr) * Wd + h * Dh + c4 * 4);
        s16x4 o;
        o[0] = f2bf(v.x); o[1] = f2bf(v.y); o[2] = f2bf(v.z); o[3] = f2bf(v.w);
        *(s16x4*)&T[sr][c4 * 4] = o;
    }
    __syncthreads();
#pragma unroll
    for (int i = 0; i < 4; ++i) {
        int f = i * 256 + tid, dr = f >> 4, s4 = f & 15;
        s16x4 o;
        o[0] = T[s4 * 4 + 0][dr]; o[1] = T[s4 * 4 + 1][dr];
        o[2] = T[s4 * 4 + 2][dr]; o[3] = T[s4 * 4 + 3][dr];
        *(s16x4*)(vt + (size_t)(bh * Dh + dr) * Sn + st * 64 + s4 * 4) = o;
    }
}

#define LSTR 40   // P-tile LDS row stride (80B: 16B-aligned, non-pow2 banks)

// ---------------------------------------------------------------------------
// Attention, BARRIER-FREE main loop. qb pre-scaled by 1/8; kb bf16; vt = V^T.
// Block 256 = 4 waves, 128 q-rows (32/wave as 2 mi-tiles). Grid 512,
// blockIdx%8 == bh%8 -> all 16 q-tiles of one (b,h) share an XCD L2.
// K-frags and V^T-frags load 16B-contiguous straight from global (L2-hot).
// P round-trip through wave-private LDS (no __syncthreads anywhere).
// No max-subtraction: scores ~ N(0,1), exp cannot overflow fp32.
// ---------------------------------------------------------------------------
__global__ __launch_bounds__(256, 2) void attn_fused(
    const short* __restrict__ qb, const short* __restrict__ kb,
    const short* __restrict__ vt, short* __restrict__ ao)
{
    __shared__ short Pl[4][2][16 * LSTR];   // [wave][mi][16q x 32s]

    const int tid  = threadIdx.x;
    const int w    = tid >> 6;
    const int l    = tid & 63;
    const int quad = l >> 4;
    const int l16  = l & 15;

    const int bh = blockIdx.x & 31;     // blk%8 = bh%8 -> XCD locality
    const int qt = blockIdx.x >> 5;
    const int b  = bh >> 4, h = bh & 15;

    const int qrow0 = qt * 128 + w * 32;

    s16x8 aq[2][2];
#pragma unroll
    for (int mi = 0; mi < 2; ++mi)
#pragma unroll
        for (int c = 0; c < 2; ++c)
            aq[mi][c] = ld8(qb + (size_t)(b * Tn + qrow0 + mi * 16 + l16) * Wd
                                 + h * Dh + c * 32 + quad * 8);

    f32x4 oacc[2][4];
    float dn[2][4];
#pragma unroll
    for (int mi = 0; mi < 2; ++mi) {
#pragma unroll
        for (int nt = 0; nt < 4; ++nt) {
            oacc[mi][nt][0] = 0.f; oacc[mi][nt][1] = 0.f;
            oacc[mi][nt][2] = 0.f; oacc[mi][nt][3] = 0.f;
        }
#pragma unroll
        for (int r = 0; r < 4; ++r) dn[mi][r] = 0.f;
    }

    const short* kb_h = kb + (size_t)(b * Sn) * Wd + h * Dh;
    const short* vt_h = vt + (size_t)(bh * Dh) * Sn;

#pragma unroll 2
    for (int it = 0; it < Sn / 32; ++it) {
        const int s0 = it * 32;
        // K B-frags (rows s, k-contiguous) and V^T B-frags (rows d, s-contiguous)
        s16x8 bk[2][2], bv[4];
#pragma unroll
        for (int n = 0; n < 2; ++n)
#pragma unroll
            for (int c = 0; c < 2; ++c)
                bk[n][c] = ld8(kb_h + (size_t)(s0 + n * 16 + l16) * Wd + c * 32 + quad * 8);
#pragma unroll
        for (int nt = 0; nt < 4; ++nt)
            bv[nt] = ld8(vt_h + (size_t)(nt * 16 + l16) * Sn + s0 + quad * 8);

#pragma unroll
        for (int mi = 0; mi < 2; ++mi) {
            const f32x4 z = {0.f, 0.f, 0.f, 0.f};
            f32x4 sc0 = MFMA(aq[mi][0], bk[0][0], z);
            sc0 = MFMA(aq[mi][1], bk[0][1], sc0);
            f32x4 sc1 = MFMA(aq[mi][0], bk[1][0], z);
            sc1 = MFMA(aq[mi][1], bk[1][1], sc1);
            short* Pw = &Pl[w][mi][0];
#pragma unroll
            for (int r = 0; r < 4; ++r) {
                short t0 = f2bf_tr(__expf(sc0[r]));   // q pre-scaled by 1/8
                short t1 = f2bf_tr(__expf(sc1[r]));
                dn[mi][r] += bf2f(t0) + bf2f(t1);     // consistent with P bits
                Pw[(quad * 4 + r) * LSTR + l16]      = t0;
                Pw[(quad * 4 + r) * LSTR + 16 + l16] = t1;
            }
            __asm__ __volatile__("" ::: "memory");    // keep LDS write->read order
            s16x8 ap = *(const s16x8*)&Pw[l16 * LSTR + quad * 8];
#pragma unroll
            for (int nt = 0; nt < 4; ++nt)
                oacc[mi][nt] = MFMA(ap, bv[nt], oacc[mi][nt]);
        }
    }

    // epilogue: reduce den across 16 column-lanes, normalize, store bf16 ws
#pragma unroll
    for (int mi = 0; mi < 2; ++mi)
#pragma unroll
        for (int r = 0; r < 4; ++r) {
            float d = dn[mi][r];
            d += __shfl_xor(d, 1);
            d += __shfl_xor(d, 2);
            d += __shfl_xor(d, 4);
            d += __shfl_xor(d, 8);
            float inv = 1.0f / d;
            int t = qrow0 + mi * 16 + quad * 4 + r;
#pragma unroll
            for (int nt = 0; nt < 4; ++nt)
                ao[(size_t)(b * Tn + t) * Wd + h * Dh + nt * 16 + l16] =
                    f2bf(oacc[mi][nt][r] * inv);
        }
}

// ---------------------------------------------------------------------------
// Projection, BARRIER-FREE, no LDS: out = A(bf16) @ Wb(bf16,[N][K])^T + bias.
// Both operands are K-contiguous -> direct 16B global fragment loads.
// Block 256 = 4 waves; tile 64m x 64n; wave = 16m x 64n. Grid 1024 (16 w/CU).
// ---------------------------------------------------------------------------
__global__ __launch_bounds__(256, 2) void proj_gemm(
    const short* __restrict__ A, const short* __restrict__ Wb,
    const float* __restrict__ bias, float* __restrict__ out)
{
    const int tid  = threadIdx.x;
    const int w    = tid >> 6;
    const int l    = tid & 63;
    const int quad = l >> 4;
    const int l16  = l & 15;

    const int bn = blockIdx.x & 15;    // 1024/64 = 16 n-tiles
    const int bm = blockIdx.x >> 4;    // 4096/64 = 64 m-tiles
    const int m0 = bm * 64 + w * 16;
    const int n0 = bn * 64;

    f32x4 acc[4];
#pragma unroll
    for (int nt = 0; nt < 4; ++nt) {
        acc[nt][0] = 0.f; acc[nt][1] = 0.f; acc[nt][2] = 0.f; acc[nt][3] = 0.f;
    }

#pragma unroll 2
    for (int k0 = 0; k0 < Wd; k0 += 32) {
        s16x8 a = ld8(A + (size_t)(m0 + l16) * Wd + k0 + quad * 8);
#pragma unroll
        for (int nt = 0; nt < 4; ++nt) {
            s16x8 bw = ld8(Wb + (size_t)(n0 + nt * 16 + l16) * Wd + k0 + quad * 8);
            acc[nt] = MFMA(a, bw, acc[nt]);
        }
    }

#pragma unroll
    for (int nt = 0; nt < 4; ++nt) {
        float bv = bias[n0 + nt * 16 + l16];
#pragma unroll
        for (int r = 0; r < 4; ++r)
            out[(size_t)(m0 + quad * 4 + r) * Wd + n0 + nt * 16 + l16] = acc[nt][r] + bv;
    }
}

extern "C" void kernel_launch(void* const* d_in, const int* in_sizes, int n_in,
                              void* d_out, int out_size, void* d_ws, size_t ws_size,
                              hipStream_t stream) {
    const float* x  = (const float*)d_in[0];   // [2,2048,1024] fp32
    const float* ck = (const float*)d_in[1];   // [2,2048,1024] fp32
    const float* cv = (const float*)d_in[2];   // [2,2048,1024] fp32
    const float* wp = (const float*)d_in[3];   // [1024,1024]   fp32
    const float* bp = (const float*)d_in[4];   // [1024]        fp32

    const int nX = Bn * Tn * Wd;   // 4,194,304
    const int nW = Wd * Wd;        // 1,048,576

    short* qb  = (short*)d_ws;     // 8 MB  (x * 1/8, bf16)
    short* kbb = qb  + nX;         // 8 MB
    short* vtb = kbb + nX;         // 8 MB  (V^T [bh][d][s])
    short* wbb = vtb + nX;         // 2 MB
    short* am  = wbb + nW;         // 8 MB  (attention output, bf16)

    cvt_scale<<<dim3(nX / 2048), dim3(256), 0, stream>>>(x,  qb,  nX, 0.125f);
    cvt_scale<<<dim3(nX / 2048), dim3(256), 0, stream>>>(ck, kbb, nX, 1.0f);
    cvt_scale<<<dim3(nW / 2048), dim3(256), 0, stream>>>(wp, wbb, nW, 1.0f);
    vtrans<<<dim3(1024), dim3(256), 0, stream>>>(cv, vtb);

    attn_fused<<<dim3(Bn * Hn * (Tn / 128)), dim3(256), 0, stream>>>(qb, kbb, vtb, am);
    proj_gemm<<<dim3((Bn * Tn / 64) * (Wd / 64)), dim3(256), 0, stream>>>(
        am, wbb, bp, (float*)d_out);
}

// Round 9
// 268.309 us; speedup vs baseline: 1.4074x; 1.0935x over previous
//
#include <hip/hip_runtime.h>

#define Bn 2
#define Hn 16
#define Tn 2048
#define Sn 2048
#define Wd 1024
#define Dh 64

typedef __attribute__((ext_vector_type(8))) short s16x8;
typedef __attribute__((ext_vector_type(4))) short s16x4;
typedef __attribute__((ext_vector_type(4))) float f32x4;

#define MFMA(a, b, c) __builtin_amdgcn_mfma_f32_16x16x32_bf16((a), (b), (c), 0, 0, 0)

__device__ __forceinline__ s16x8 ld8(const short* p) { return *(const s16x8*)p; }

// fp32 -> bf16 round-to-nearest-even
__device__ __forceinline__ short f2bf(float f) {
    unsigned u = __builtin_bit_cast(unsigned, f);
    u += 0x7FFFu + ((u >> 16) & 1u);
    return (short)(u >> 16);
}

// ---------------------------------------------------------------------------
// fp32 -> bf16 bulk convert with scale (8 elems/thread, coalesced)
// ---------------------------------------------------------------------------
__global__ void cvt_scale(const float* __restrict__ in, short* __restrict__ out,
                          int n, float s) {
    int i = (blockIdx.x * 256 + threadIdx.x) * 8;
    if (i < n) {
        float4 a = *(const float4*)(in + i);
        float4 b = *(const float4*)(in + i + 4);
        s16x8 o;
        o[0] = f2bf(a.x * s); o[1] = f2bf(a.y * s); o[2] = f2bf(a.z * s); o[3] = f2bf(a.w * s);
        o[4] = f2bf(b.x * s); o[5] = f2bf(b.y * s); o[6] = f2bf(b.z * s); o[7] = f2bf(b.w * s);
        *(s16x8*)(out + i) = o;
    }
}

// ---------------------------------------------------------------------------
// V -> V^T bf16 with within-32 s-interleave: storage position p in each
// 32-chunk holds s = (p&1)*16 + (p>>1). Matches the P-tile dword packing in
// attn (dot products are k-order invariant, so QK^T's s-order permutation is
// absorbed as long as P and V use the SAME order).
// vt[(b*16+h)*64+d][pos], pos in [0,Sn).  64x64 tiles via LDS.
// ---------------------------------------------------------------------------
__global__ __launch_bounds__(256) void vtrans(const float* __restrict__ cv,
                                              short* __restrict__ vt) {
    __shared__ short T[64][68];
    const int st = blockIdx.x & 31;          // s tile (64 wide)
    const int bh = blockIdx.x >> 5;          // 0..31
    const int b = bh >> 4, h = bh & 15;
    const int tid = threadIdx.x;
#pragma unroll
    for (int i = 0; i < 4; ++i) {
        int f = i * 256 + tid, sr = f >> 4, c4 = f & 15;
        float4 v = *(const float4*)(cv + (size_t)(b * Sn + st * 64 + sr) * Wd + h * Dh + c4 * 4);
        s16x4 o;
        o[0] = f2bf(v.x); o[1] = f2bf(v.y); o[2] = f2bf(v.z); o[3] = f2bf(v.w);
        *(s16x4*)&T[sr][c4 * 4] = o;
    }
    __syncthreads();
#pragma unroll
    for (int i = 0; i < 4; ++i) {
        int f = i * 256 + tid, dr = f >> 4, p4 = f & 15;
        s16x4 o;
#pragma unroll
        for (int k = 0; k < 4; ++k) {
            int p = p4 * 4 + k;                       // output position in tile
            int g = p >> 5, pi = p & 31;
            int sl = g * 32 + ((pi & 1) * 16 + (pi >> 1));  // source s in tile
            o[k] = T[sl][dr];
        }
        *(s16x4*)(vt + (size_t)(bh * Dh + dr) * Sn + st * 64 + p4 * 4) = o;
    }
}

#define LSTR 40   // P row stride in shorts (80 B: 16B-aligned, non-pow2 banks)

// ---------------------------------------------------------------------------
// Attention, barrier-free main loop, in-block S-split.
// qb = x * (0.125*log2e) bf16; kb bf16; vt = permuted V^T bf16.
// Block 512 thr = 8 waves = 4 q-groups x 2 S-halves; 128 q-rows/block.
// Grid 512 (blk%8 = bh%8 -> XCD L2 locality). 16 waves/CU.
// P:  C/D (row=quad*4+r,col=l16) -> packed dword (sc0,sc1) -> LDS [q][p]
//     (p-interleaved) -> b128 A-frags. exp via raw v_exp_f32 (2^x).
// End: S-halves combined through LDS (2 barriers total).
// ---------------------------------------------------------------------------
__global__ __launch_bounds__(512, 4) void attn_fused(
    const short* __restrict__ qb, const short* __restrict__ kb,
    const short* __restrict__ vt, short* __restrict__ ao)
{
    // union: main loop uses P tiles (8 waves x 2 parity x 2 mi x 16xLSTR shorts
    //        = 40960 B); combine phase reuses as Cb[4][32][64]f32 + Db[4][32]f32
    __shared__ __align__(16) char raw[4 * 32 * 64 * 4 + 4 * 32 * 4 + 8192];

    const int tid  = threadIdx.x;
    const int w    = tid >> 6;          // 0..7
    const int sp   = w >> 2;            // S-half
    const int qg   = w & 3;             // q-group
    const int l    = tid & 63;
    const int quad = l >> 4;
    const int l16  = l & 15;

    const int bh = blockIdx.x & 31;     // blk%8 = bh%8 -> XCD locality
    const int qt = blockIdx.x >> 5;
    const int b  = bh >> 4, h = bh & 15;

    const int qrow0 = qt * 128 + qg * 32;

    s16x8 aq[2][2];
#pragma unroll
    for (int mi = 0; mi < 2; ++mi)
#pragma unroll
        for (int c = 0; c < 2; ++c)
            aq[mi][c] = ld8(qb + (size_t)(b * Tn + qrow0 + mi * 16 + l16) * Wd
                                 + h * Dh + c * 32 + quad * 8);

    f32x4 oacc[2][4];
    float dn[2][4];
#pragma unroll
    for (int mi = 0; mi < 2; ++mi) {
#pragma unroll
        for (int nt = 0; nt < 4; ++nt) {
            oacc[mi][nt][0] = 0.f; oacc[mi][nt][1] = 0.f;
            oacc[mi][nt][2] = 0.f; oacc[mi][nt][3] = 0.f;
        }
#pragma unroll
        for (int r = 0; r < 4; ++r) dn[mi][r] = 0.f;
    }

    const short* kb_h = kb + (size_t)(b * Sn) * Wd + h * Dh + (size_t)(sp * 1024) * Wd;
    const short* vt_h = vt + (size_t)(bh * Dh) * Sn + sp * 1024;

#pragma unroll 2
    for (int it = 0; it < 32; ++it) {
        const int s0 = it * 32;
        short* Pw = (short*)raw + ((it & 1) * 8 + w) * (2 * 16 * LSTR);

        s16x8 bk[2][2], bv[4];
#pragma unroll
        for (int n = 0; n < 2; ++n)
#pragma unroll
            for (int c = 0; c < 2; ++c)
                bk[n][c] = ld8(kb_h + (size_t)(s0 + n * 16 + l16) * Wd + c * 32 + quad * 8);
#pragma unroll
        for (int nt = 0; nt < 4; ++nt)
            bv[nt] = ld8(vt_h + (size_t)(nt * 16 + l16) * Sn + s0 + quad * 8);

        // QK for both mi (4 independent 2-chains)
        f32x4 sc[2][2];
        const f32x4 z = {0.f, 0.f, 0.f, 0.f};
#pragma unroll
        for (int mi = 0; mi < 2; ++mi) {
            sc[mi][0] = MFMA(aq[mi][0], bk[0][0], z);
            sc[mi][0] = MFMA(aq[mi][1], bk[0][1], sc[mi][0]);
            sc[mi][1] = MFMA(aq[mi][0], bk[1][0], z);
            sc[mi][1] = MFMA(aq[mi][1], bk[1][1], sc[mi][1]);
        }
        // exp (2^x, q pre-scaled), truncate to bf16, pack pairs, write b32
#pragma unroll
        for (int mi = 0; mi < 2; ++mi) {
#pragma unroll
            for (int r = 0; r < 4; ++r) {
                unsigned u0 = __builtin_bit_cast(unsigned, __builtin_amdgcn_exp2f(sc[mi][0][r]));
                unsigned u1 = __builtin_bit_cast(unsigned, __builtin_amdgcn_exp2f(sc[mi][1][r]));
                unsigned hi = u1 & 0xFFFF0000u;
                unsigned pk = (u0 >> 16) | hi;          // (lo=t0, hi=t1)
                dn[mi][r] += __builtin_bit_cast(float, u0 & 0xFFFF0000u)
                           + __builtin_bit_cast(float, hi);
                *(unsigned*)&Pw[mi * (16 * LSTR) + (quad * 4 + r) * LSTR + l16 * 2] = pk;
            }
        }
        __asm__ __volatile__("" ::: "memory");   // keep LDS write->read order
        s16x8 ap0 = *(const s16x8*)&Pw[l16 * LSTR + quad * 8];
        s16x8 ap1 = *(const s16x8*)&Pw[16 * LSTR + l16 * LSTR + quad * 8];
#pragma unroll
        for (int nt = 0; nt < 4; ++nt) {
            oacc[0][nt] = MFMA(ap0, bv[nt], oacc[0][nt]);
            oacc[1][nt] = MFMA(ap1, bv[nt], oacc[1][nt]);
        }
    }

    // per-wave denominator reduce across the 16 column-lanes
#pragma unroll
    for (int mi = 0; mi < 2; ++mi)
#pragma unroll
        for (int r = 0; r < 4; ++r) {
            float d = dn[mi][r];
            d += __shfl_xor(d, 1);
            d += __shfl_xor(d, 2);
            d += __shfl_xor(d, 4);
            d += __shfl_xor(d, 8);
            dn[mi][r] = d;
        }

    // ---- combine the two S-halves through LDS ----
    float* Cb = (float*)raw;                    // [4][32][64]
    float* Db = (float*)(raw + 4 * 32 * 64 * 4);// [4][32]
    __syncthreads();                            // all P-tile use done
    if (sp == 1) {
        float* C = Cb + qg * (32 * 64);
        float* D = Db + qg * 32;
#pragma unroll
        for (int mi = 0; mi < 2; ++mi) {
#pragma unroll
            for (int r = 0; r < 4; ++r) {
                int row = mi * 16 + quad * 4 + r;
#pragma unroll
                for (int nt = 0; nt < 4; ++nt)
                    C[row * 64 + nt * 16 + l16] = oacc[mi][nt][r];
                if (l16 == 0) D[row] = dn[mi][r];
            }
        }
    }
    __syncthreads();
    if (sp == 0) {
        const float* C = Cb + qg * (32 * 64);
        const float* D = Db + qg * 32;
#pragma unroll
        for (int mi = 0; mi < 2; ++mi) {
#pragma unroll
            for (int r = 0; r < 4; ++r) {
                int row = mi * 16 + quad * 4 + r;
                float inv = 1.0f / (dn[mi][r] + D[row]);
                int t = qrow0 + row;
#pragma unroll
                for (int nt = 0; nt < 4; ++nt) {
                    float v = oacc[mi][nt][r] + C[row * 64 + nt * 16 + l16];
                    ao[(size_t)(b * Tn + t) * Wd + h * Dh + nt * 16 + l16] = f2bf(v * inv);
                }
            }
        }
    }
}

// ---------------------------------------------------------------------------
// Projection, barrier-free, no LDS: out = A(bf16) @ Wb(bf16,[N][K])^T + bias.
// Block 256 = 4 waves; block tile 128m x 64n; wave 32m x 64n (8 MFMA / 6 frags
// per 32-k). Grid 512 (2 blocks/CU, 8 waves/CU); Wb (2 MB) L2-hot.
// ---------------------------------------------------------------------------
__global__ __launch_bounds__(256, 2) void proj_gemm(
    const short* __restrict__ A, const short* __restrict__ Wb,
    const float* __restrict__ bias, float* __restrict__ out)
{
    const int tid  = threadIdx.x;
    const int w    = tid >> 6;
    const int l    = tid & 63;
    const int quad = l >> 4;
    const int l16  = l & 15;

    const int bn = blockIdx.x & 15;    // 16 n-tiles
    const int bm = blockIdx.x >> 4;    // 32 m-tiles
    const int m0 = bm * 128 + w * 32;
    const int n0 = bn * 64;

    f32x4 acc[2][4];
#pragma unroll
    for (int mi = 0; mi < 2; ++mi)
#pragma unroll
        for (int nt = 0; nt < 4; ++nt) {
            acc[mi][nt][0] = 0.f; acc[mi][nt][1] = 0.f;
            acc[mi][nt][2] = 0.f; acc[mi][nt][3] = 0.f;
        }

#pragma unroll 2
    for (int k0 = 0; k0 < Wd; k0 += 32) {
        s16x8 a[2], bw[4];
#pragma unroll
        for (int mi = 0; mi < 2; ++mi)
            a[mi] = ld8(A + (size_t)(m0 + mi * 16 + l16) * Wd + k0 + quad * 8);
#pragma unroll
        for (int nt = 0; nt < 4; ++nt)
            bw[nt] = ld8(Wb + (size_t)(n0 + nt * 16 + l16) * Wd + k0 + quad * 8);
#pragma unroll
        for (int mi = 0; mi < 2; ++mi)
#pragma unroll
            for (int nt = 0; nt < 4; ++nt)
                acc[mi][nt] = MFMA(a[mi], bw[nt], acc[mi][nt]);
    }

#pragma unroll
    for (int nt = 0; nt < 4; ++nt) {
        float bv = bias[n0 + nt * 16 + l16];
#pragma unroll
        for (int mi = 0; mi < 2; ++mi)
#pragma unroll
            for (int r = 0; r < 4; ++r)
                out[(size_t)(m0 + mi * 16 + quad * 4 + r) * Wd + n0 + nt * 16 + l16] =
                    acc[mi][nt][r] + bv;
    }
}

extern "C" void kernel_launch(void* const* d_in, const int* in_sizes, int n_in,
                              void* d_out, int out_size, void* d_ws, size_t ws_size,
                              hipStream_t stream) {
    const float* x  = (const float*)d_in[0];   // [2,2048,1024] fp32
    const float* ck = (const float*)d_in[1];   // [2,2048,1024] fp32
    const float* cv = (const float*)d_in[2];   // [2,2048,1024] fp32
    const float* wp = (const float*)d_in[3];   // [1024,1024]   fp32
    const float* bp = (const float*)d_in[4];   // [1024]        fp32

    const int nX = Bn * Tn * Wd;   // 4,194,304
    const int nW = Wd * Wd;        // 1,048,576

    short* qb  = (short*)d_ws;     // 8 MB  (x * 0.125*log2e, bf16)
    short* kbb = qb  + nX;         // 8 MB
    short* vtb = kbb + nX;         // 8 MB  (permuted V^T [bh][d][pos])
    short* wbb = vtb + nX;         // 2 MB
    short* am  = wbb + nW;         // 8 MB  (attention output, bf16)

    const float SQ = 0.125f * 1.4426950408889634f;   // fold 1/sqrt(d) and log2e

    cvt_scale<<<dim3(nX / 2048), dim3(256), 0, stream>>>(x,  qb,  nX, SQ);
    cvt_scale<<<dim3(nX / 2048), dim3(256), 0, stream>>>(ck, kbb, nX, 1.0f);
    cvt_scale<<<dim3(nW / 2048), dim3(256), 0, stream>>>(wp, wbb, nW, 1.0f);
    vtrans<<<dim3(1024), dim3(256), 0, stream>>>(cv, vtb);

    attn_fused<<<dim3(Bn * Hn * (Tn / 128)), dim3(512), 0, stream>>>(qb, kbb, vtb, am);
    proj_gemm<<<dim3((Bn * Tn / 128) * (Wd / 64)), dim3(256), 0, stream>>>(
        am, wbb, bp, (float*)d_out);
}

// Round 10
// 178.675 us; speedup vs baseline: 2.1134x; 1.5017x over previous
//
#include <hip/hip_runtime.h>

#define Bn 2
#define Hn 16
#define Tn 2048
#define Sn 2048
#define Wd 1024
#define Dh 64

typedef __attribute__((ext_vector_type(8))) short s16x8;
typedef __attribute__((ext_vector_type(4))) short s16x4;
typedef __attribute__((ext_vector_type(4))) float f32x4;

#define MFMA(a, b, c) __builtin_amdgcn_mfma_f32_16x16x32_bf16((a), (b), (c), 0, 0, 0)

__device__ __forceinline__ s16x8 ld8(const short* p) { return *(const s16x8*)p; }

// fp32 -> bf16 round-to-nearest-even
__device__ __forceinline__ short f2bf(float f) {
    unsigned u = __builtin_bit_cast(unsigned, f);
    u += 0x7FFFu + ((u >> 16) & 1u);
    return (short)(u >> 16);
}

// ---------------------------------------------------------------------------
// fp32 -> bf16 bulk convert with scale (8 elems/thread, coalesced)
// ---------------------------------------------------------------------------
__global__ void cvt_scale(const float* __restrict__ in, short* __restrict__ out,
                          int n, float s) {
    int i = (blockIdx.x * 256 + threadIdx.x) * 8;
    if (i < n) {
        float4 a = *(const float4*)(in + i);
        float4 b = *(const float4*)(in + i + 4);
        s16x8 o;
        o[0] = f2bf(a.x * s); o[1] = f2bf(a.y * s); o[2] = f2bf(a.z * s); o[3] = f2bf(a.w * s);
        o[4] = f2bf(b.x * s); o[5] = f2bf(b.y * s); o[6] = f2bf(b.z * s); o[7] = f2bf(b.w * s);
        *(s16x8*)(out + i) = o;
    }
}

// ---------------------------------------------------------------------------
// V -> V^T bf16 with within-32 s-interleave: position p in each 32-chunk
// holds s = (p&1)*16 + (p>>1) — matches attn's packed-dword P layout
// (dot products are k-order invariant as long as P and V^T agree).
// vt[(b*16+h)*64+d][pos].  64x64 tiles via LDS.
// ---------------------------------------------------------------------------
__global__ __launch_bounds__(256) void vtrans(const float* __restrict__ cv,
                                              short* __restrict__ vt) {
    __shared__ short T[64][68];
    const int st = blockIdx.x & 31;          // s tile (64 wide)
    const int bh = blockIdx.x >> 5;          // 0..31
    const int b = bh >> 4, h = bh & 15;
    const int tid = threadIdx.x;
#pragma unroll
    for (int i = 0; i < 4; ++i) {
        int f = i * 256 + tid, sr = f >> 4, c4 = f & 15;
        float4 v = *(const float4*)(cv + (size_t)(b * Sn + st * 64 + sr) * Wd + h * Dh + c4 * 4);
        s16x4 o;
        o[0] = f2bf(v.x); o[1] = f2bf(v.y); o[2] = f2bf(v.z); o[3] = f2bf(v.w);
        *(s16x4*)&T[sr][c4 * 4] = o;
    }
    __syncthreads();
#pragma unroll
    for (int i = 0; i < 4; ++i) {
        int f = i * 256 + tid, dr = f >> 4, p4 = f & 15;
        s16x4 o;
#pragma unroll
        for (int k = 0; k < 4; ++k) {
            int p = p4 * 4 + k;
            int g = p >> 5, pi = p & 31;
            int sl = g * 32 + ((pi & 1) * 16 + (pi >> 1));
            o[k] = T[sl][dr];
        }
        *(s16x4*)(vt + (size_t)(bh * Dh + dr) * Sn + st * 64 + p4 * 4) = o;
    }
}

#define KSTR 72   // K/V/P LDS row stride in shorts (144 B = 9*16: b128-aligned,
                  // 4*l16-bank pattern -> 2 lanes/bank = conflict-free)

// ---------------------------------------------------------------------------
// Attention with block-cooperative LDS tile staging (m93 structure).
// Block 256 thr = 4 waves; 128 q-rows (32/wave); S-chunk 64.
// K-tile [s][d] and V^T-tile [d][pos] staged ONCE per block with coalesced
// loads (each L2 line touched once per block, not once per wave).
// QK: 16 MFMA/wave; exp2 (q pre-scaled by 0.125*log2e); P packed-dword ->
// wave-private LDS -> b128 A-frags; PV: 16 MFMA/wave.
// Grid 512, blk%8 = bh%8 -> XCD L2 locality.
// ---------------------------------------------------------------------------
__global__ __launch_bounds__(256, 2) void attn_fused(
    const float* __restrict__ x, const short* __restrict__ kb,
    const short* __restrict__ vt, short* __restrict__ ao)
{
    __shared__ short Ks[64 * KSTR];          // 9.2 KB
    __shared__ short Vs[64 * KSTR];          // 9.2 KB
    __shared__ short Pt[4][32 * KSTR];       // 18.4 KB (per-wave P tiles)

    const int tid  = threadIdx.x;
    const int w    = tid >> 6;
    const int l    = tid & 63;
    const int quad = l >> 4;
    const int l16  = l & 15;

    const int bh = blockIdx.x & 31;          // blk%8 = bh%8 -> XCD locality
    const int qt = blockIdx.x >> 5;
    const int b  = bh >> 4, h = bh & 15;

    const int qrow0 = qt * 128 + w * 32;

    // Q A-frags from fp32, scaled by 0.125*log2e (folds 1/sqrt(d) and exp2 base)
    const float SQ = 0.125f * 1.4426950408889634f;
    s16x8 aq[2][2];
#pragma unroll
    for (int mi = 0; mi < 2; ++mi)
#pragma unroll
        for (int c = 0; c < 2; ++c) {
            const float* p = x + (size_t)(b * Tn + qrow0 + mi * 16 + l16) * Wd
                               + h * Dh + c * 32 + quad * 8;
            float4 a = ((const float4*)p)[0], bb = ((const float4*)p)[1];
            s16x8 o;
            o[0] = f2bf(a.x * SQ); o[1] = f2bf(a.y * SQ); o[2] = f2bf(a.z * SQ); o[3] = f2bf(a.w * SQ);
            o[4] = f2bf(bb.x * SQ); o[5] = f2bf(bb.y * SQ); o[6] = f2bf(bb.z * SQ); o[7] = f2bf(bb.w * SQ);
            aq[mi][c] = o;
        }

    f32x4 oacc[2][4];
    float dn[2][4];
#pragma unroll
    for (int mi = 0; mi < 2; ++mi) {
#pragma unroll
        for (int nt = 0; nt < 4; ++nt) {
            oacc[mi][nt][0] = 0.f; oacc[mi][nt][1] = 0.f;
            oacc[mi][nt][2] = 0.f; oacc[mi][nt][3] = 0.f;
        }
#pragma unroll
        for (int r = 0; r < 4; ++r) dn[mi][r] = 0.f;
    }

    const short* kb_h = kb + (size_t)(b * Sn) * Wd + h * Dh;
    const short* vt_h = vt + (size_t)(bh * Dh) * Sn;

    const int sr = tid >> 3;   // staging row 0..31 (two passes: +0, +32)
    const int sg = tid & 7;    // 16B segment 0..7 within a 128B row

    short* Pw = &Pt[w][0];

    for (int it = 0; it < Sn / 64; ++it) {
        const int s0 = it * 64;
        __syncthreads();   // previous chunk's tiles fully consumed
#pragma unroll
        for (int i = 0; i < 2; ++i) {
            int r0 = sr + i * 32;
            *(s16x8*)&Ks[r0 * KSTR + sg * 8] = ld8(kb_h + (size_t)(s0 + r0) * Wd + sg * 8);
            *(s16x8*)&Vs[r0 * KSTR + sg * 8] = ld8(vt_h + (size_t)r0 * Sn + s0 + sg * 8);
        }
        __syncthreads();   // tiles ready

        // ---- QK: sc[mi][sj] over 64 s ----
        f32x4 sc[2][4];
        const f32x4 z = {0.f, 0.f, 0.f, 0.f};
#pragma unroll
        for (int sj = 0; sj < 4; ++sj) {
            s16x8 k0 = *(const s16x8*)&Ks[(sj * 16 + l16) * KSTR + quad * 8];
            s16x8 k1 = *(const s16x8*)&Ks[(sj * 16 + l16) * KSTR + 32 + quad * 8];
#pragma unroll
            for (int mi = 0; mi < 2; ++mi) {
                sc[mi][sj] = MFMA(aq[mi][0], k0, z);
                sc[mi][sj] = MFMA(aq[mi][1], k1, sc[mi][sj]);
            }
        }

        // ---- exp2, pack pairs (sj=2g, 2g+1) into dwords, write P ----
#pragma unroll
        for (int mi = 0; mi < 2; ++mi)
#pragma unroll
            for (int g = 0; g < 2; ++g)
#pragma unroll
                for (int r = 0; r < 4; ++r) {
                    unsigned u0 = __builtin_bit_cast(unsigned, __builtin_amdgcn_exp2f(sc[mi][2 * g][r]));
                    unsigned u1 = __builtin_bit_cast(unsigned, __builtin_amdgcn_exp2f(sc[mi][2 * g + 1][r]));
                    unsigned hi = u1 & 0xFFFF0000u;
                    unsigned pk = (u0 >> 16) | hi;
                    dn[mi][r] += __builtin_bit_cast(float, u0 & 0xFFFF0000u)
                               + __builtin_bit_cast(float, hi);
                    *(unsigned*)&Pw[(mi * 16 + quad * 4 + r) * KSTR + g * 32 + l16 * 2] = pk;
                }
        __asm__ __volatile__("" ::: "memory");   // keep LDS write->read order

        // ---- PV: oacc[mi][nt] += P[mi] x V^T ----
        s16x8 ap[2][2], bv[4][2];
#pragma unroll
        for (int mi = 0; mi < 2; ++mi)
#pragma unroll
            for (int g = 0; g < 2; ++g)
                ap[mi][g] = *(const s16x8*)&Pw[(mi * 16 + l16) * KSTR + g * 32 + quad * 8];
#pragma unroll
        for (int nt = 0; nt < 4; ++nt)
#pragma unroll
            for (int g = 0; g < 2; ++g)
                bv[nt][g] = *(const s16x8*)&Vs[(nt * 16 + l16) * KSTR + g * 32 + quad * 8];
#pragma unroll
        for (int mi = 0; mi < 2; ++mi)
#pragma unroll
            for (int nt = 0; nt < 4; ++nt) {
                oacc[mi][nt] = MFMA(ap[mi][0], bv[nt][0], oacc[mi][nt]);
                oacc[mi][nt] = MFMA(ap[mi][1], bv[nt][1], oacc[mi][nt]);
            }
    }

    // epilogue: reduce den across the 16 column-lanes, normalize, store bf16
#pragma unroll
    for (int mi = 0; mi < 2; ++mi)
#pragma unroll
        for (int r = 0; r < 4; ++r) {
            float d = dn[mi][r];
            d += __shfl_xor(d, 1);
            d += __shfl_xor(d, 2);
            d += __shfl_xor(d, 4);
            d += __shfl_xor(d, 8);
            float inv = 1.0f / d;
            int t = qrow0 + mi * 16 + quad * 4 + r;
#pragma unroll
            for (int nt = 0; nt < 4; ++nt)
                ao[(size_t)(b * Tn + t) * Wd + h * Dh + nt * 16 + l16] =
                    f2bf(oacc[mi][nt][r] * inv);
        }
}

#define LSTR 40   // proj LDS row stride (80 B = 5*16: b128-aligned, 2-way banks)

// ---------------------------------------------------------------------------
// Projection, LDS-staged GEMM (m92/m93 structure):
// out[4096][1024] = A(bf16)[M][K] @ Wb(bf16)[N][K]^T + bias, fp32 out.
// Block 256 = 4 waves; tile 128m x 64n x 32k; wave = 64m x 32n (8 MFMA/chunk).
// Grid 512 -> 2 blocks/CU. Tiles staged coopera­tively (lines touched once/block).
// ---------------------------------------------------------------------------
__global__ __launch_bounds__(256, 2) void proj_gemm(
    const short* __restrict__ A, const short* __restrict__ Wb,
    const float* __restrict__ bias, float* __restrict__ out)
{
    __shared__ short As[128 * LSTR];
    __shared__ short Bs[64 * LSTR];

    const int tid  = threadIdx.x;
    const int w    = tid >> 6;
    const int l    = tid & 63;
    const int quad = l >> 4;
    const int l16  = l & 15;

    const int bn = blockIdx.x & 15;    // 16 n-tiles
    const int bm = blockIdx.x >> 4;    // 32 m-tiles
    const int m0 = bm * 128;
    const int n0 = bn * 64;
    const int wm = (w & 1) * 64;       // wave m-offset
    const int wn = (w >> 1) * 32;      // wave n-offset

    const int rr = tid >> 2;   // staging row 0..63
    const int sg = tid & 3;    // 16B segment 0..3 (BK=32 shorts = 64B row)

    f32x4 acc[4][2];
#pragma unroll
    for (int mi = 0; mi < 4; ++mi)
#pragma unroll
        for (int nt = 0; nt < 2; ++nt) {
            acc[mi][nt][0] = 0.f; acc[mi][nt][1] = 0.f;
            acc[mi][nt][2] = 0.f; acc[mi][nt][3] = 0.f;
        }

    for (int k0 = 0; k0 < Wd; k0 += 32) {
        __syncthreads();
        *(s16x8*)&As[rr * LSTR + sg * 8]        = ld8(A  + (size_t)(m0 + rr) * Wd + k0 + sg * 8);
        *(s16x8*)&As[(rr + 64) * LSTR + sg * 8] = ld8(A  + (size_t)(m0 + 64 + rr) * Wd + k0 + sg * 8);
        *(s16x8*)&Bs[rr * LSTR + sg * 8]        = ld8(Wb + (size_t)(n0 + rr) * Wd + k0 + sg * 8);
        __syncthreads();

        s16x8 a[4], bw[2];
#pragma unroll
        for (int mi = 0; mi < 4; ++mi)
            a[mi] = *(const s16x8*)&As[(wm + mi * 16 + l16) * LSTR + quad * 8];
#pragma unroll
        for (int nt = 0; nt < 2; ++nt)
            bw[nt] = *(const s16x8*)&Bs[(wn + nt * 16 + l16) * LSTR + quad * 8];
#pragma unroll
        for (int mi = 0; mi < 4; ++mi)
#pragma unroll
            for (int nt = 0; nt < 2; ++nt)
                acc[mi][nt] = MFMA(a[mi], bw[nt], acc[mi][nt]);
    }

#pragma unroll
    for (int nt = 0; nt < 2; ++nt) {
        float bv = bias[n0 + wn + nt * 16 + l16];
#pragma unroll
        for (int mi = 0; mi < 4; ++mi)
#pragma unroll
            for (int r = 0; r < 4; ++r)
                out[(size_t)(m0 + wm + mi * 16 + quad * 4 + r) * Wd + n0 + wn + nt * 16 + l16] =
                    acc[mi][nt][r] + bv;
    }
}

extern "C" void kernel_launch(void* const* d_in, const int* in_sizes, int n_in,
                              void* d_out, int out_size, void* d_ws, size_t ws_size,
                              hipStream_t stream) {
    const float* x  = (const float*)d_in[0];   // [2,2048,1024] fp32
    const float* ck = (const float*)d_in[1];   // [2,2048,1024] fp32
    const float* cv = (const float*)d_in[2];   // [2,2048,1024] fp32
    const float* wp = (const float*)d_in[3];   // [1024,1024]   fp32
    const float* bp = (const float*)d_in[4];   // [1024]        fp32

    const int nX = Bn * Tn * Wd;   // 4,194,304
    const int nW = Wd * Wd;        // 1,048,576

    short* kbb = (short*)d_ws;     // 8 MB  (K bf16)
    short* vtb = kbb + nX;         // 8 MB  (permuted V^T [bh][d][pos])
    short* wbb = vtb + nX;         // 2 MB  (Wp bf16)
    short* am  = wbb + nW;         // 8 MB  (attention output, bf16)

    cvt_scale<<<dim3(nX / 2048), dim3(256), 0, stream>>>(ck, kbb, nX, 1.0f);
    cvt_scale<<<dim3(nW / 2048), dim3(256), 0, stream>>>(wp, wbb, nW, 1.0f);
    vtrans<<<dim3(1024), dim3(256), 0, stream>>>(cv, vtb);

    attn_fused<<<dim3(Bn * Hn * (Tn / 128)), dim3(256), 0, stream>>>(x, kbb, vtb, am);
    proj_gemm<<<dim3((Bn * Tn / 128) * (Wd / 64)), dim3(256), 0, stream>>>(
        am, wbb, bp, (float*)d_out);
}